// Round 6
// baseline (106.838 us; speedup 1.0000x reference)
//
#include <hip/hip_runtime.h>
#include <math.h>

// B=1024, D=128, H=128
#define Bn 1024
#define Dn 128
#define Hn 128
#define REP 2  // phase-1 repeated identically for rocprof visibility (calibration)

// 256 blocks x 1024 threads (16 waves/CU, 1 block/CU). Block owns 4 i-rows.
// Phase 1 (double-buffered LDS staging): j runs in 16 tiles of 64 rows.
//   Stage tile k+1 (32 KB, fully coalesced float4, all 16 waves) into
//   buf[(k+1)&1] while computing tile k from buf[k&1] via ds_read_b64.
//   Thread (q = t>>6 in [0,16) -> j's q*4..q*4+3 of the tile, c2 = t&63 ->
//   cols 2c2,2c2+1) accumulates 4 rows x 2 cols; 64 VALU instrs per tile.
// Phase 2: LDS tree-reduce 16 q-groups -> dms.
// Phases 3-5: tau, matvecs, LayerNorm (verified epilogue, t<256).
__global__ __launch_bounds__(1024) void fused_resd1(
    const float* __restrict__ x,
    const float* __restrict__ Wd, const float* __restrict__ bd,
    const float* __restrict__ Wt, const float* __restrict__ bt,
    const float* __restrict__ Wa, const float* __restrict__ ba,
    const float* __restrict__ Wr, const float* __restrict__ br,
    const float* __restrict__ gamma, const float* __restrict__ beta,
    float* __restrict__ out) {
  const int t = threadIdx.x;
  const int c2 = t & 63;   // col pair: cols 2c2, 2c2+1
  const int q = t >> 6;    // j-subgroup in [0,16) (== wave id)
  const int i0 = blockIdx.x << 2;

  __shared__ float buf[2][64 * Dn];  // 64 KB: double-buffered j-tiles
  __shared__ float red[16][4][Dn];   // 32 KB: per-q partial column sums
  __shared__ float xs[4][Dn];
  __shared__ float dms[4][Dn];
  __shared__ float ms[4][Hn];
  __shared__ float ys[4][Hn];
  __shared__ float wt_s[Dn];
  __shared__ float tau_s[4];         // 1/tau

  // ---- Phase 1 ----
  float2 xi[4];
#pragma unroll
  for (int r = 0; r < 4; ++r)
    xi[r] = *(const float2*)(x + (size_t)(i0 + r) * Dn + 2 * c2);

  const float4* gx = (const float4*)x;
  const int lane = t & 63;
  const int fa = (t >> 6) * 128 + lane;  // local float4 index (wave-contiguous)

  float2 acc[4];
#pragma unroll 1
  for (int rep = 0; rep < REP; ++rep) {
#pragma unroll
    for (int r = 0; r < 4; ++r) acc[r] = make_float2(0.f, 0.f);

    // prime tile 0
    float4 s0 = gx[fa];
    float4 s1 = gx[fa + 64];
    __syncthreads();  // prev rep's last-tile compute done before overwriting buf[0]
    *(float4*)&buf[0][fa * 4] = s0;
    *(float4*)&buf[0][fa * 4 + 256] = s1;

#pragma unroll 1
    for (int k = 0; k < 16; ++k) {
      float4 n0, n1;
      if (k < 15) {  // issue next tile's loads before the barrier (in flight across it)
        n0 = gx[(size_t)(k + 1) * 2048 + fa];
        n1 = gx[(size_t)(k + 1) * 2048 + fa + 64];
      }
      __syncthreads();  // buf[k&1] fully staged
      const float* tb = buf[k & 1];
#pragma unroll
      for (int u = 0; u < 4; ++u) {
        const float2 xj = *(const float2*)&tb[(q * 4 + u) * Dn + 2 * c2];
#pragma unroll
        for (int r = 0; r < 4; ++r) {
          acc[r].x += fabsf(xi[r].x - xj.x);
          acc[r].y += fabsf(xi[r].y - xj.y);
        }
      }
      if (k < 15) {
        *(float4*)&buf[(k + 1) & 1][fa * 4] = n0;
        *(float4*)&buf[(k + 1) & 1][fa * 4 + 256] = n1;
      }
    }
  }
#pragma unroll
  for (int r = 0; r < 4; ++r) *(float2*)&red[q][r][2 * c2] = acc[r];
  __syncthreads();

  // ---- Phase 2: reduce 16 q-groups; stage xs, wt_s ----
  if (t < 512) {
    const int r = t >> 7, d = t & 127;
    float s = 0.f;
#pragma unroll
    for (int qq = 0; qq < 16; ++qq) s += red[qq][r][d];
    dms[r][d] = s * (1.0f / 1024.0f);
    xs[r][d] = x[(size_t)(i0 + r) * Dn + d];
  } else if (t < 640) {
    wt_s[t - 512] = Wt[t - 512];
  }
  __syncthreads();

  // ---- Phase 3: tau (one wave per row, t<256) ----
  if (t < 256) {
    const int r = t >> 6, p = t & 63;
    float partial = xs[r][p] * wt_s[p] + xs[r][p + 64] * wt_s[p + 64];
#pragma unroll
    for (int off = 32; off; off >>= 1) partial += __shfl_xor(partial, off, 64);
    if (p == 0) {
      const float z = partial + bt[0];
      const float sp = fmaxf(z, 0.f) + log1pf(expf(-fabsf(z)));  // softplus
      tau_s[r] = 1.0f / (fmaxf(sp, 0.01f) + 1.0f);
    }
  }
  __syncthreads();

  // ---- Phase 4a: m = (Wd . dm + bd) / tau (t<256) ----
  if (t < 256) {
    const int h = t & 127;
    const int g4 = t >> 7;
    const int r0 = 2 * g4, r1 = 2 * g4 + 1;
    float m0 = bd[h], m1 = m0;
    const float4* w = (const float4*)(Wd + (size_t)h * Dn);
#pragma unroll 4
    for (int k4 = 0; k4 < Dn / 4; ++k4) {
      const float4 wv = w[k4];
      const int k = k4 * 4;
      m0 += wv.x * dms[r0][k] + wv.y * dms[r0][k + 1] + wv.z * dms[r0][k + 2] + wv.w * dms[r0][k + 3];
      m1 += wv.x * dms[r1][k] + wv.y * dms[r1][k + 1] + wv.z * dms[r1][k + 2] + wv.w * dms[r1][k + 3];
    }
    ms[r0][h] = m0 * tau_s[r0];
    ms[r1][h] = m1 * tau_s[r1];
  }
  __syncthreads();

  // ---- Phase 4b: y = relu(Wa . m + ba) + Wr . x + br (t<256) ----
  if (t < 256) {
    const int h = t & 127;
    const int g4 = t >> 7;
    const int r0 = 2 * g4, r1 = 2 * g4 + 1;
    float q0 = ba[h], q1 = q0, c0 = br[h], c1 = c0;
    const float4* wa = (const float4*)(Wa + (size_t)h * Dn);
    const float4* wr = (const float4*)(Wr + (size_t)h * Dn);
#pragma unroll 4
    for (int k4 = 0; k4 < Dn / 4; ++k4) {
      const float4 av = wa[k4];
      const float4 rv = wr[k4];
      const int k = k4 * 4;
      q0 += av.x * ms[r0][k] + av.y * ms[r0][k + 1] + av.z * ms[r0][k + 2] + av.w * ms[r0][k + 3];
      q1 += av.x * ms[r1][k] + av.y * ms[r1][k + 1] + av.z * ms[r1][k + 2] + av.w * ms[r1][k + 3];
      c0 += rv.x * xs[r0][k] + rv.y * xs[r0][k + 1] + rv.z * xs[r0][k + 2] + rv.w * xs[r0][k + 3];
      c1 += rv.x * xs[r1][k] + rv.y * xs[r1][k + 1] + rv.z * xs[r1][k + 2] + rv.w * xs[r1][k + 3];
    }
    ys[r0][h] = fmaxf(q0, 0.f) + c0;
    ys[r1][h] = fmaxf(q1, 0.f) + c1;
  }
  __syncthreads();

  // ---- Phase 5: LayerNorm (one wave per row, t<256) ----
  if (t < 256) {
    const int r = t >> 6, p = t & 63;
    const float v0 = ys[r][p], v1 = ys[r][p + 64];
    float s = v0 + v1;
    float qq = v0 * v0 + v1 * v1;
#pragma unroll
    for (int off = 32; off; off >>= 1) {
      s += __shfl_xor(s, off, 64);
      qq += __shfl_xor(qq, off, 64);
    }
    const float mu = s * (1.0f / 128.0f);
    const float var = qq * (1.0f / 128.0f) - mu * mu;
    const float rs = rsqrtf(var + 1e-5f);
    float* o = out + (size_t)(i0 + r) * Hn;
    o[p]      = (v0 - mu) * rs * gamma[p]      + beta[p];
    o[p + 64] = (v1 - mu) * rs * gamma[p + 64] + beta[p + 64];
  }
}

extern "C" void kernel_launch(void* const* d_in, const int* in_sizes, int n_in,
                              void* d_out, int out_size, void* d_ws, size_t ws_size,
                              hipStream_t stream) {
  const float* x     = (const float*)d_in[0];
  const float* Wd    = (const float*)d_in[1];
  const float* bd    = (const float*)d_in[2];
  const float* Wt    = (const float*)d_in[3];
  const float* bt    = (const float*)d_in[4];
  const float* Wa    = (const float*)d_in[5];
  const float* ba    = (const float*)d_in[6];
  const float* Wr    = (const float*)d_in[7];
  const float* br    = (const float*)d_in[8];
  const float* gamma = (const float*)d_in[9];
  const float* beta  = (const float*)d_in[10];
  float* out = (float*)d_out;

  fused_resd1<<<Bn / 4, 1024, 0, stream>>>(x, Wd, bd, Wt, bt, Wa, ba, Wr, br,
                                           gamma, beta, out);
  (void)in_sizes; (void)n_in; (void)out_size; (void)d_ws; (void)ws_size;
}